// Round 9
// baseline (986.118 us; speedup 1.0000x reference)
//
#include <hip/hip_runtime.h>
#include <hip/hip_bf16.h>

// LightweightMambaCodec: B=16 L=512 DIN=64 DM=256 DI=512 NL=2 LAT=128 N=16 K=4 R=16
// R8: scan n-split — thread = (b,d,half), 8 n-states per thread, 2x wave count
// (512->1024 blocks) for latency hiding. dt-proj duplicated per half (keeps scalar
// dbl loads); y combined with one quad-perm shfl; half0/half1 split y_hi/y_lo store.
// GEMMs and everything else unchanged from R6.

#define DEVINL __device__ __forceinline__

typedef unsigned short u16;
typedef unsigned int u32;
typedef short bf16x8 __attribute__((ext_vector_type(8)));
typedef float f32x4 __attribute__((ext_vector_type(4)));
typedef u16 ushort8 __attribute__((ext_vector_type(8)));
typedef u16 ushort4v __attribute__((ext_vector_type(4)));

constexpr int MROWS = 16 * 512; // 8192

DEVINL float silu_f(float x) { return x / (1.f + __expf(-x)); }
DEVINL float softplus_f(float x) { return (x > 20.f) ? x : log1pf(__expf(x)); }

DEVINL u16 f2bf(float x) {
  __hip_bfloat16 h = __float2bfloat16(x);
  return *reinterpret_cast<u16*>(&h);
}
DEVINL float bf2f(u16 u) {
  __hip_bfloat16 h;
  *reinterpret_cast<u16*>(&h) = u;
  return __bfloat162float(h);
}

// ---------------- split pre-pass ----------------
struct SplitList {
  const float* src[9];
  u16* hi[9];
  u16* lo[9];
  int n4[9];
};

__global__ __launch_bounds__(256) void split_kernel(SplitList sl, int total4) {
  int i = blockIdx.x * 256 + threadIdx.x;
  if (i >= total4) return;
  int t = 0, off = i;
  while (off >= sl.n4[t]) { off -= sl.n4[t]; ++t; }
  float4 v = *(const float4*)(sl.src[t] + (size_t)off * 4);
  float vv[4] = {v.x, v.y, v.z, v.w};
  ushort4v h, l;
  #pragma unroll
  for (int j = 0; j < 4; j++) {
    u16 hb = f2bf(vv[j]);
    h[j] = hb;
    l[j] = f2bf(vv[j] - bf2f(hb));
  }
  *(ushort4v*)(sl.hi[t] + (size_t)off * 4) = h;
  *(ushort4v*)(sl.lo[t] + (size_t)off * 4) = l;
}

// ---------------- split-bf16 MFMA GEMM (unchanged) ----------------
template<bool BIAS, bool FOUT, bool SPLITOUT>
__global__ __launch_bounds__(256) void gemm_mfma(
    const u16* __restrict__ Ah, const u16* __restrict__ Al, int lda,
    const u16* __restrict__ Wh, const u16* __restrict__ Wl,
    const float* __restrict__ bias,
    float* __restrict__ C, u16* __restrict__ Chi, u16* __restrict__ Clo,
    int M, int N, int K)
{
  constexpr int BKP = 40;
  __shared__ u16 As[2][128][BKP];
  __shared__ u16 Ws[2][64][BKP];
  const int tid = threadIdx.x;
  const int bn0 = blockIdx.x * 64;
  const int bm0 = blockIdx.y * 128;
  const int w = tid >> 6, l = tid & 63;
  const int wm = w >> 1, wn = w & 1;
  const int lr = l & 15, lk = l >> 4;

  f32x4 acc[4][2] = {};

  for (int k0 = 0; k0 < K; k0 += 32) {
    #pragma unroll
    for (int q = 0; q < 2; q++) {
      int idx = tid + 256 * q;
      int r = idx >> 2, c8 = (idx & 3) * 8;
      size_t g = (size_t)(bm0 + r) * lda + k0 + c8;
      *(ushort8*)&As[0][r][c8] = *(const ushort8*)(Ah + g);
      *(ushort8*)&As[1][r][c8] = *(const ushort8*)(Al + g);
    }
    {
      int r = tid >> 2, c8 = (tid & 3) * 8;
      ushort8 vh = {0,0,0,0,0,0,0,0}, vl = {0,0,0,0,0,0,0,0};
      if (bn0 + r < N) {
        size_t g = (size_t)(bn0 + r) * K + k0 + c8;
        vh = *(const ushort8*)(Wh + g);
        vl = *(const ushort8*)(Wl + g);
      }
      *(ushort8*)&Ws[0][r][c8] = vh;
      *(ushort8*)&Ws[1][r][c8] = vl;
    }
    __syncthreads();

    bf16x8 afh[4], afl[4], wfh[2], wfl[2];
    #pragma unroll
    for (int i = 0; i < 4; i++) {
      int r = wm * 64 + i * 16 + lr;
      afh[i] = *(const bf16x8*)&As[0][r][lk * 8];
      afl[i] = *(const bf16x8*)&As[1][r][lk * 8];
    }
    #pragma unroll
    for (int j = 0; j < 2; j++) {
      int r = wn * 32 + j * 16 + lr;
      wfh[j] = *(const bf16x8*)&Ws[0][r][lk * 8];
      wfl[j] = *(const bf16x8*)&Ws[1][r][lk * 8];
    }
    #pragma unroll
    for (int i = 0; i < 4; i++)
      #pragma unroll
      for (int j = 0; j < 2; j++) {
        acc[i][j] = __builtin_amdgcn_mfma_f32_16x16x32_bf16(afh[i], wfh[j], acc[i][j], 0, 0, 0);
        acc[i][j] = __builtin_amdgcn_mfma_f32_16x16x32_bf16(afh[i], wfl[j], acc[i][j], 0, 0, 0);
        acc[i][j] = __builtin_amdgcn_mfma_f32_16x16x32_bf16(afl[i], wfh[j], acc[i][j], 0, 0, 0);
      }
    __syncthreads();
  }

  #pragma unroll
  for (int i = 0; i < 4; i++)
    #pragma unroll
    for (int j = 0; j < 2; j++) {
      int col = bn0 + wn * 32 + j * 16 + lr;
      if (col < N) {
        float bv = BIAS ? bias[col] : 0.f;
        #pragma unroll
        for (int rr = 0; rr < 4; rr++) {
          int row = bm0 + wm * 64 + i * 16 + lk * 4 + rr;
          float v = acc[i][j][rr] + bv;
          size_t o = (size_t)row * N + col;
          if constexpr (FOUT) C[o] = v;
          if constexpr (SPLITOUT) {
            u16 hb = f2bf(v);
            Chi[o] = hb;
            Clo[o] = f2bf(v - bf2f(hb));
          }
        }
      }
    }
}

// depthwise causal conv K=4, + bias + silu; outputs split bf16 xc
__global__ __launch_bounds__(256) void conv_silu_kernel(
    const float* __restrict__ xz,
    const float* __restrict__ convw,
    const float* __restrict__ convb,
    u16* __restrict__ xch, u16* __restrict__ xcl)
{
  int idx = blockIdx.x * 256 + threadIdx.x;
  int d = idx & 511;
  int l = (idx >> 9) & 511;
  int b = idx >> 18;
  float acc = convb[d];
  #pragma unroll
  for (int k = 0; k < 4; k++) {
    int ll = l - 3 + k;
    if (ll >= 0) acc += convw[d * 4 + k] * xz[((size_t)(b * 512 + ll)) * 1024 + d];
  }
  float v = silu_f(acc);
  u16 hb = f2bf(v);
  xch[idx] = hb;
  xcl[idx] = f2bf(v - bf2f(hb));
}

// ---------------- chunked scan, register-state, n-split ----------------
// ps/hs layout: [c:16][b:16][n:16][d:512]; thread = (b,d,half), 8 n-states each.

__global__ __launch_bounds__(256) void scan_part1(
    const u16* __restrict__ xch, const u16* __restrict__ xcl,
    const float* __restrict__ dbl,
    const float* __restrict__ Wdt, const float* __restrict__ bdt,
    const float* __restrict__ Alog,
    float2* __restrict__ ps)
{
  int bx = blockIdx.x;                       // 1024 blocks
  int c = bx & 15, b = (bx >> 4) & 15, dg = bx >> 8;   // dg 0..3
  int tid = threadIdx.x;
  int dl = tid >> 1, half = tid & 1;
  int d = dg * 128 + dl;
  int t0 = c * 32;

  float wdt[16];
  #pragma unroll
  for (int q = 0; q < 4; q++) {
    float4 w4 = *(const float4*)(Wdt + d * 16 + q * 4);
    wdt[q * 4 + 0] = w4.x; wdt[q * 4 + 1] = w4.y; wdt[q * 4 + 2] = w4.z; wdt[q * 4 + 3] = w4.w;
  }
  float A8[8];
  #pragma unroll
  for (int q = 0; q < 2; q++) {
    float4 a4 = *(const float4*)(Alog + d * 16 + half * 8 + q * 4);
    A8[q * 4 + 0] = -__expf(a4.x); A8[q * 4 + 1] = -__expf(a4.y);
    A8[q * 4 + 2] = -__expf(a4.z); A8[q * 4 + 3] = -__expf(a4.w);
  }
  float bdtv = bdt[d];
  float S8[8], P8[8];
  #pragma unroll
  for (int n = 0; n < 8; n++) { S8[n] = 0.f; P8[n] = 1.f; }

  const float* dblb = dbl + (size_t)(b * 512 + t0) * 48;
  const u16* uph = xch + (size_t)(b * 512 + t0) * 512 + d;
  const u16* upl = xcl + (size_t)(b * 512 + t0) * 512 + d;

  for (int t = 0; t < 32; t++) {
    const float* dr = dblb + t * 48;
    float dtv = bdtv;
    #pragma unroll
    for (int q = 0; q < 4; q++) {
      float4 r4 = *(const float4*)(dr + q * 4);
      dtv += r4.x * wdt[q * 4 + 0] + r4.y * wdt[q * 4 + 1]
           + r4.z * wdt[q * 4 + 2] + r4.w * wdt[q * 4 + 3];
    }
    dtv = softplus_f(dtv);
    float u = bf2f(uph[t * 512]) + bf2f(upl[t * 512]);
    float w = dtv * u;
    #pragma unroll
    for (int q = 0; q < 2; q++) {
      float4 B4 = *(const float4*)(dr + 16 + half * 8 + q * 4);
      float Bj[4] = {B4.x, B4.y, B4.z, B4.w};
      #pragma unroll
      for (int j = 0; j < 4; j++) {
        int n = q * 4 + j;
        float a = __expf(dtv * A8[n]);
        S8[n] = a * S8[n] + w * Bj[j];
        P8[n] *= a;
      }
    }
  }
  float2* pp = ps + (size_t)c * 131072 + b * 8192 + d;
  #pragma unroll
  for (int n = 0; n < 8; n++)
    pp[(size_t)(half * 8 + n) * 512] = make_float2(P8[n], S8[n]);
}

__global__ __launch_bounds__(256) void scan_part2(
    const float2* __restrict__ ps, float* __restrict__ hs)
{
  int idx = blockIdx.x * 256 + threadIdx.x; // 131072 = (b,n,d)
  float h = 0.f;
  #pragma unroll
  for (int c = 0; c < 16; c++) {
    float2 v = ps[(size_t)c * 131072 + idx];
    hs[(size_t)c * 131072 + idx] = h;
    h = v.x * h + v.y;
  }
}

__global__ __launch_bounds__(256) void scan_part3(
    const u16* __restrict__ xch, const u16* __restrict__ xcl,
    const float* __restrict__ dbl,
    const float* __restrict__ xz,   // z at col 512
    const float* __restrict__ Wdt, const float* __restrict__ bdt,
    const float* __restrict__ Alog, const float* __restrict__ Dp,
    const float* __restrict__ hs,
    u16* __restrict__ yh, u16* __restrict__ yl)
{
  int bx = blockIdx.x;                       // 1024 blocks
  int c = bx & 15, b = (bx >> 4) & 15, dg = bx >> 8;
  int tid = threadIdx.x;
  int dl = tid >> 1, half = tid & 1;
  int d = dg * 128 + dl;
  int t0 = c * 32;

  float wdt[16];
  #pragma unroll
  for (int q = 0; q < 4; q++) {
    float4 w4 = *(const float4*)(Wdt + d * 16 + q * 4);
    wdt[q * 4 + 0] = w4.x; wdt[q * 4 + 1] = w4.y; wdt[q * 4 + 2] = w4.z; wdt[q * 4 + 3] = w4.w;
  }
  float A8[8];
  #pragma unroll
  for (int q = 0; q < 2; q++) {
    float4 a4 = *(const float4*)(Alog + d * 16 + half * 8 + q * 4);
    A8[q * 4 + 0] = -__expf(a4.x); A8[q * 4 + 1] = -__expf(a4.y);
    A8[q * 4 + 2] = -__expf(a4.z); A8[q * 4 + 3] = -__expf(a4.w);
  }
  float bdtv = bdt[d];
  float Dv = Dp[d];
  float h8[8];
  {
    const float* hp = hs + (size_t)c * 131072 + b * 8192 + d;
    #pragma unroll
    for (int n = 0; n < 8; n++) h8[n] = hp[(size_t)(half * 8 + n) * 512];
  }

  const float* dblb = dbl + (size_t)(b * 512 + t0) * 48;
  const u16* uph = xch + (size_t)(b * 512 + t0) * 512 + d;
  const u16* upl = xcl + (size_t)(b * 512 + t0) * 512 + d;
  const float* zp = xz + (size_t)(b * 512 + t0) * 1024 + 512 + d;
  u16* yhp = yh + (size_t)(b * 512 + t0) * 512 + d;
  u16* ylp = yl + (size_t)(b * 512 + t0) * 512 + d;

  for (int t = 0; t < 32; t++) {
    const float* dr = dblb + t * 48;
    float dtv = bdtv;
    #pragma unroll
    for (int q = 0; q < 4; q++) {
      float4 r4 = *(const float4*)(dr + q * 4);
      dtv += r4.x * wdt[q * 4 + 0] + r4.y * wdt[q * 4 + 1]
           + r4.z * wdt[q * 4 + 2] + r4.w * wdt[q * 4 + 3];
    }
    dtv = softplus_f(dtv);
    float u = bf2f(uph[t * 512]) + bf2f(upl[t * 512]);
    float w = dtv * u;
    float y = 0.f;
    #pragma unroll
    for (int q = 0; q < 2; q++) {
      float4 B4 = *(const float4*)(dr + 16 + half * 8 + q * 4);
      float4 C4 = *(const float4*)(dr + 32 + half * 8 + q * 4);
      float Bj[4] = {B4.x, B4.y, B4.z, B4.w};
      float Cj[4] = {C4.x, C4.y, C4.z, C4.w};
      #pragma unroll
      for (int j = 0; j < 4; j++) {
        int n = q * 4 + j;
        float a = __expf(dtv * A8[n]);
        h8[n] = a * h8[n] + w * Bj[j];
        y += h8[n] * Cj[j];
      }
    }
    y += __shfl_xor(y, 1);                 // combine the two 8-n halves
    float zv = zp[t * 1024];
    float v = (y + u * Dv) * silu_f(zv);
    u16 hb = f2bf(v);
    if (half == 0) yhp[t * 512] = hb;       // half0 -> hi
    else           ylp[t * 512] = f2bf(v - bf2f(hb)); // half1 -> lo
  }
}

__global__ void pool_kernel(const float* __restrict__ h, float* __restrict__ pooled) {
  int b = blockIdx.x, d = threadIdx.x;
  float s = 0.f;
  for (int l = 0; l < 512; l++) s += h[((size_t)(b * 512 + l)) * 256 + d];
  pooled[b * 256 + d] = s * (1.f / 512.f);
}

__global__ void small_gemm_kernel(const float* __restrict__ A, const float* __restrict__ W,
                                  const float* __restrict__ bias, float* __restrict__ C,
                                  int Mb, int N, int K) {
  int idx = blockIdx.x * blockDim.x + threadIdx.x;
  if (idx >= Mb * N) return;
  int b = idx / N, n = idx - b * N;
  float acc = bias[n];
  for (int k = 0; k < K; k++) acc += A[b * K + k] * W[n * K + k];
  C[idx] = acc;
}

__global__ void bcast_kernel(const float* __restrict__ s, u16* __restrict__ hh, u16* __restrict__ hl) {
  int idx = blockIdx.x * 256 + threadIdx.x; // over 8192*256
  int d = idx & 255;
  int b = idx >> 17;
  float v = s[b * 256 + d];
  u16 hb = f2bf(v);
  hh[idx] = hb;
  hl[idx] = f2bf(v - bf2f(hb));
}

extern "C" void kernel_launch(void* const* d_in, const int* in_sizes, int n_in,
                              void* d_out, int out_size, void* d_ws, size_t ws_size,
                              hipStream_t stream) {
  const float* x     = (const float*)d_in[0];
  const float* emb_W = (const float*)d_in[1];
  const float* emb_b = (const float*)d_in[2];
  const float* lat_W = (const float*)d_in[3];
  const float* lat_b = (const float*)d_in[4];
  const float* l2s_W = (const float*)d_in[5];
  const float* l2s_b = (const float*)d_in[6];
  const float* out_W = (const float*)d_in[7];
  const float* out_b = (const float*)d_in[8];

  char* base = (char*)d_ws;
  float*  h      = (float*) (base + 0);          //  8,388,608 B
  float*  xz     = (float*) (base + 8388608);    // 33,554,432
  float*  dbl    = (float*) (base + 41943040);   //  1,572,864
  float2* ps     = (float2*)(base + 43515904);   // 16,777,216
  float*  hs     = (float*) (base + 60293120);   //  8,388,608
  u16*    h_hi   = (u16*)   (base + 68681728);   //  4,194,304
  u16*    h_lo   = (u16*)   (base + 72876032);   //  4,194,304
  u16*    xc_hi  = (u16*)   (base + 77070336);   //  8,388,608
  u16*    xc_lo  = (u16*)   (base + 85458944);   //  8,388,608
  u16*    x_hi   = (u16*)   (base + 93847552);   //  1,048,576
  u16*    x_lo   = (u16*)   (base + 94896128);   //  1,048,576
  u16*    w_hi   = (u16*)   (base + 95944704);   //  3,407,872
  u16*    w_lo   = (u16*)   (base + 99352576);   //  3,407,872
  float*  pooled = (float*) (base + 102760448);  //     16,384
  float*  s_sml  = (float*) (base + 102776832);  //     16,384
  // y split aliases ps (ps dead once scan_part2 consumed it; Wout runs before next part1)
  u16* y_hi = (u16*)ps;
  u16* y_lo = (u16*)((char*)ps + 8388608);

  float* recon  = (float*)d_out;      // 8192*64
  float* latent = recon + 524288;     // 16*128

  dim3 blk(256);

  // ---- split pre-pass: x + all GEMM weights ----
  SplitList sl;
  const float* srcs[9] = {x, emb_W, out_W,
                          (const float*)d_in[9],  (const float*)d_in[12], (const float*)d_in[17],
                          (const float*)d_in[18], (const float*)d_in[21], (const float*)d_in[26]};
  size_t offs[9] = {0, 0, 16384, 32768, 557056, 606208, 868352, 1392640, 1441792};
  int    n4s[9]  = {131072, 4096, 4096, 131072, 12288, 65536, 131072, 12288, 65536};
  for (int t = 0; t < 9; t++) {
    sl.src[t] = srcs[t];
    sl.hi[t] = (t == 0) ? x_hi : w_hi + offs[t];
    sl.lo[t] = (t == 0) ? x_lo : w_lo + offs[t];
    sl.n4[t] = n4s[t];
  }
  int total4 = 557056;
  hipLaunchKernelGGL(split_kernel, dim3(total4 / 256), blk, 0, stream, sl, total4);

  // h = x @ emb_W.T + emb_b  (split out only)
  hipLaunchKernelGGL((gemm_mfma<true, false, true>), dim3(4, 64), blk, 0, stream,
                     x_hi, x_lo, 64, w_hi + 0, w_lo + 0, emb_b,
                     nullptr, h_hi, h_lo, MROWS, 256, 64);

  auto run_layer = [&](int base_in, size_t wpre, int i, bool foutH) {
    const float* cw   = (const float*)d_in[base_in + 1] + (size_t)i * 512 * 4;
    const float* cb   = (const float*)d_in[base_in + 2] + (size_t)i * 512;
    const float* Wdt  = (const float*)d_in[base_in + 4] + (size_t)i * 512 * 16;
    const float* bdt  = (const float*)d_in[base_in + 5] + (size_t)i * 512;
    const float* Alog = (const float*)d_in[base_in + 6] + (size_t)i * 512 * 16;
    const float* Dpp  = (const float*)d_in[base_in + 7] + (size_t)i * 512;
    const u16* WinH  = w_hi + wpre + (size_t)i * 262144;
    const u16* WinL  = w_lo + wpre + (size_t)i * 262144;
    const u16* WxH   = w_hi + wpre + 524288 + (size_t)i * 24576;
    const u16* WxL   = w_lo + wpre + 524288 + (size_t)i * 24576;
    const u16* WoutH = w_hi + wpre + 573440 + (size_t)i * 131072;
    const u16* WoutL = w_lo + wpre + 573440 + (size_t)i * 131072;

    // xz = h @ Win.T
    hipLaunchKernelGGL((gemm_mfma<false, true, false>), dim3(16, 64), blk, 0, stream,
                       h_hi, h_lo, 256, WinH, WinL, nullptr, xz, nullptr, nullptr, MROWS, 1024, 256);
    // xc = silu(conv(xz[:, :512]) + cb) -> split
    hipLaunchKernelGGL(conv_silu_kernel, dim3(MROWS * 512 / 256), blk, 0, stream,
                       xz, cw, cb, xc_hi, xc_lo);
    // dbl = xc @ Wx.T (N=48)
    hipLaunchKernelGGL((gemm_mfma<false, true, false>), dim3(1, 64), blk, 0, stream,
                       xc_hi, xc_lo, 512, WxH, WxL, nullptr, dbl, nullptr, nullptr, MROWS, 48, 512);
    // chunked scan (dt fused, register-state, n-split)
    hipLaunchKernelGGL(scan_part1, dim3(1024), blk, 0, stream,
                       xc_hi, xc_lo, dbl, Wdt, bdt, Alog, ps);
    hipLaunchKernelGGL(scan_part2, dim3(131072 / 256), blk, 0, stream,
                       (const float2*)ps, hs);
    hipLaunchKernelGGL(scan_part3, dim3(1024), blk, 0, stream,
                       xc_hi, xc_lo, dbl, xz, Wdt, bdt, Alog, Dpp, hs, y_hi, y_lo);
    // h = y @ Wout.T
    if (foutH)
      hipLaunchKernelGGL((gemm_mfma<false, true, true>), dim3(4, 64), blk, 0, stream,
                         y_hi, y_lo, 512, WoutH, WoutL, nullptr, h, h_hi, h_lo, MROWS, 256, 512);
    else
      hipLaunchKernelGGL((gemm_mfma<false, false, true>), dim3(4, 64), blk, 0, stream,
                         y_hi, y_lo, 512, WoutH, WoutL, nullptr, nullptr, h_hi, h_lo, MROWS, 256, 512);
  };

  run_layer(9, 32768, 0, false);
  run_layer(9, 32768, 1, true);   // pool needs f32 h

  hipLaunchKernelGGL(pool_kernel, dim3(16), blk, 0, stream, h, pooled);
  hipLaunchKernelGGL(small_gemm_kernel, dim3((16 * 128 + 255) / 256), blk, 0, stream,
                     pooled, lat_W, lat_b, latent, 16, 128, 256);
  hipLaunchKernelGGL(small_gemm_kernel, dim3((16 * 256 + 255) / 256), blk, 0, stream,
                     latent, l2s_W, l2s_b, s_sml, 16, 256, 128);
  hipLaunchKernelGGL(bcast_kernel, dim3(8192 * 256 / 256), blk, 0, stream, s_sml, h_hi, h_lo);

  run_layer(18, 868352, 0, false);
  run_layer(18, 868352, 1, false);

  // recon = h @ out_W.T + out_b
  hipLaunchKernelGGL((gemm_mfma<true, true, false>), dim3(1, 64), blk, 0, stream,
                     h_hi, h_lo, 256, w_hi + 16384, w_lo + 16384, out_b,
                     recon, nullptr, nullptr, MROWS, 64, 256);
}

// Round 12
// 778.381 us; speedup vs baseline: 1.2669x; 1.2669x over previous
//
#include <hip/hip_runtime.h>
#include <hip/hip_bf16.h>

// LightweightMambaCodec: B=16 L=512 DIN=64 DM=256 DI=512 NL=2 LAT=128 N=16 K=4 R=16
// R9 (3rd submit; prior two runs hit GPU acquisition timeouts): revert scan to R6
// register-state form (n-split regressed); part1 stores dt into dead xz[:, :512]
// (conv input, consumed before part1) so part3 skips the dt-projection; P via
// exp(A*sum(dt)); unroll-2 t-loops. GEMMs unchanged.

#define DEVINL __device__ __forceinline__

typedef unsigned short u16;
typedef unsigned int u32;
typedef short bf16x8 __attribute__((ext_vector_type(8)));
typedef float f32x4 __attribute__((ext_vector_type(4)));
typedef u16 ushort8 __attribute__((ext_vector_type(8)));
typedef u16 ushort4v __attribute__((ext_vector_type(4)));

constexpr int MROWS = 16 * 512; // 8192

DEVINL float silu_f(float x) { return x / (1.f + __expf(-x)); }
DEVINL float softplus_f(float x) { return (x > 20.f) ? x : log1pf(__expf(x)); }

DEVINL u16 f2bf(float x) {
  __hip_bfloat16 h = __float2bfloat16(x);
  return *reinterpret_cast<u16*>(&h);
}
DEVINL float bf2f(u16 u) {
  __hip_bfloat16 h;
  *reinterpret_cast<u16*>(&h) = u;
  return __bfloat162float(h);
}

// ---------------- split pre-pass ----------------
struct SplitList {
  const float* src[9];
  u16* hi[9];
  u16* lo[9];
  int n4[9];
};

__global__ __launch_bounds__(256) void split_kernel(SplitList sl, int total4) {
  int i = blockIdx.x * 256 + threadIdx.x;
  if (i >= total4) return;
  int t = 0, off = i;
  while (off >= sl.n4[t]) { off -= sl.n4[t]; ++t; }
  float4 v = *(const float4*)(sl.src[t] + (size_t)off * 4);
  float vv[4] = {v.x, v.y, v.z, v.w};
  ushort4v h, l;
  #pragma unroll
  for (int j = 0; j < 4; j++) {
    u16 hb = f2bf(vv[j]);
    h[j] = hb;
    l[j] = f2bf(vv[j] - bf2f(hb));
  }
  *(ushort4v*)(sl.hi[t] + (size_t)off * 4) = h;
  *(ushort4v*)(sl.lo[t] + (size_t)off * 4) = l;
}

// ---------------- split-bf16 MFMA GEMM (unchanged) ----------------
template<bool BIAS, bool FOUT, bool SPLITOUT>
__global__ __launch_bounds__(256) void gemm_mfma(
    const u16* __restrict__ Ah, const u16* __restrict__ Al, int lda,
    const u16* __restrict__ Wh, const u16* __restrict__ Wl,
    const float* __restrict__ bias,
    float* __restrict__ C, u16* __restrict__ Chi, u16* __restrict__ Clo,
    int M, int N, int K)
{
  constexpr int BKP = 40;
  __shared__ u16 As[2][128][BKP];
  __shared__ u16 Ws[2][64][BKP];
  const int tid = threadIdx.x;
  const int bn0 = blockIdx.x * 64;
  const int bm0 = blockIdx.y * 128;
  const int w = tid >> 6, l = tid & 63;
  const int wm = w >> 1, wn = w & 1;
  const int lr = l & 15, lk = l >> 4;

  f32x4 acc[4][2] = {};

  for (int k0 = 0; k0 < K; k0 += 32) {
    #pragma unroll
    for (int q = 0; q < 2; q++) {
      int idx = tid + 256 * q;
      int r = idx >> 2, c8 = (idx & 3) * 8;
      size_t g = (size_t)(bm0 + r) * lda + k0 + c8;
      *(ushort8*)&As[0][r][c8] = *(const ushort8*)(Ah + g);
      *(ushort8*)&As[1][r][c8] = *(const ushort8*)(Al + g);
    }
    {
      int r = tid >> 2, c8 = (tid & 3) * 8;
      ushort8 vh = {0,0,0,0,0,0,0,0}, vl = {0,0,0,0,0,0,0,0};
      if (bn0 + r < N) {
        size_t g = (size_t)(bn0 + r) * K + k0 + c8;
        vh = *(const ushort8*)(Wh + g);
        vl = *(const ushort8*)(Wl + g);
      }
      *(ushort8*)&Ws[0][r][c8] = vh;
      *(ushort8*)&Ws[1][r][c8] = vl;
    }
    __syncthreads();

    bf16x8 afh[4], afl[4], wfh[2], wfl[2];
    #pragma unroll
    for (int i = 0; i < 4; i++) {
      int r = wm * 64 + i * 16 + lr;
      afh[i] = *(const bf16x8*)&As[0][r][lk * 8];
      afl[i] = *(const bf16x8*)&As[1][r][lk * 8];
    }
    #pragma unroll
    for (int j = 0; j < 2; j++) {
      int r = wn * 32 + j * 16 + lr;
      wfh[j] = *(const bf16x8*)&Ws[0][r][lk * 8];
      wfl[j] = *(const bf16x8*)&Ws[1][r][lk * 8];
    }
    #pragma unroll
    for (int i = 0; i < 4; i++)
      #pragma unroll
      for (int j = 0; j < 2; j++) {
        acc[i][j] = __builtin_amdgcn_mfma_f32_16x16x32_bf16(afh[i], wfh[j], acc[i][j], 0, 0, 0);
        acc[i][j] = __builtin_amdgcn_mfma_f32_16x16x32_bf16(afh[i], wfl[j], acc[i][j], 0, 0, 0);
        acc[i][j] = __builtin_amdgcn_mfma_f32_16x16x32_bf16(afl[i], wfh[j], acc[i][j], 0, 0, 0);
      }
    __syncthreads();
  }

  #pragma unroll
  for (int i = 0; i < 4; i++)
    #pragma unroll
    for (int j = 0; j < 2; j++) {
      int col = bn0 + wn * 32 + j * 16 + lr;
      if (col < N) {
        float bv = BIAS ? bias[col] : 0.f;
        #pragma unroll
        for (int rr = 0; rr < 4; rr++) {
          int row = bm0 + wm * 64 + i * 16 + lk * 4 + rr;
          float v = acc[i][j][rr] + bv;
          size_t o = (size_t)row * N + col;
          if constexpr (FOUT) C[o] = v;
          if constexpr (SPLITOUT) {
            u16 hb = f2bf(v);
            Chi[o] = hb;
            Clo[o] = f2bf(v - bf2f(hb));
          }
        }
      }
    }
}

// depthwise causal conv K=4, + bias + silu; outputs split bf16 xc
__global__ __launch_bounds__(256) void conv_silu_kernel(
    const float* __restrict__ xz,
    const float* __restrict__ convw,
    const float* __restrict__ convb,
    u16* __restrict__ xch, u16* __restrict__ xcl)
{
  int idx = blockIdx.x * 256 + threadIdx.x;
  int d = idx & 511;
  int l = (idx >> 9) & 511;
  int b = idx >> 18;
  float acc = convb[d];
  #pragma unroll
  for (int k = 0; k < 4; k++) {
    int ll = l - 3 + k;
    if (ll >= 0) acc += convw[d * 4 + k] * xz[((size_t)(b * 512 + ll)) * 1024 + d];
  }
  float v = silu_f(acc);
  u16 hb = f2bf(v);
  xch[idx] = hb;
  xcl[idx] = f2bf(v - bf2f(hb));
}

// ---------------- chunked scan, register-state (R6 form) ----------------
// ps/hs layout: [c:16][b:16][n:16][d:512]; thread = (b,d), 16 n-states in regs.
// part1 stores dt into xz[:, :512] (dead after conv); part3 reloads it.

__global__ __launch_bounds__(256) void scan_part1(
    const u16* __restrict__ xch, const u16* __restrict__ xcl,
    const float* __restrict__ dbl,
    const float* __restrict__ Wdt, const float* __restrict__ bdt,
    const float* __restrict__ Alog,
    float2* __restrict__ ps,
    float* __restrict__ xzdt)          // xz base; dt written at cols [0,512)
{
  int bx = blockIdx.x;                 // 512 blocks
  int c = bx & 15, b = (bx >> 4) & 15, dg = bx >> 8;
  int d = dg * 256 + threadIdx.x;
  int t0 = c * 32;

  float wdt[16], A[16];
  #pragma unroll
  for (int q = 0; q < 4; q++) {
    float4 w4 = *(const float4*)(Wdt + d * 16 + q * 4);
    wdt[q * 4 + 0] = w4.x; wdt[q * 4 + 1] = w4.y; wdt[q * 4 + 2] = w4.z; wdt[q * 4 + 3] = w4.w;
    float4 a4 = *(const float4*)(Alog + d * 16 + q * 4);
    A[q * 4 + 0] = -__expf(a4.x); A[q * 4 + 1] = -__expf(a4.y);
    A[q * 4 + 2] = -__expf(a4.z); A[q * 4 + 3] = -__expf(a4.w);
  }
  float bdtv = bdt[d];
  float S[16];
  #pragma unroll
  for (int n = 0; n < 16; n++) S[n] = 0.f;
  float dtsum = 0.f;

  const float* dblb = dbl + (size_t)(b * 512 + t0) * 48;  // wave-uniform
  const u16* uph = xch + (size_t)(b * 512 + t0) * 512 + d;
  const u16* upl = xcl + (size_t)(b * 512 + t0) * 512 + d;
  float* dtp = xzdt + (size_t)(b * 512 + t0) * 1024 + d;

  #pragma unroll 2
  for (int t = 0; t < 32; t++) {
    const float* dr = dblb + t * 48;
    float dtv = bdtv;
    #pragma unroll
    for (int q = 0; q < 4; q++) {
      float4 r4 = *(const float4*)(dr + q * 4);
      dtv += r4.x * wdt[q * 4 + 0] + r4.y * wdt[q * 4 + 1]
           + r4.z * wdt[q * 4 + 2] + r4.w * wdt[q * 4 + 3];
    }
    dtv = softplus_f(dtv);
    dtp[(size_t)t * 1024] = dtv;
    dtsum += dtv;
    float u = bf2f(uph[t * 512]) + bf2f(upl[t * 512]);
    float w = dtv * u;
    #pragma unroll
    for (int q = 0; q < 4; q++) {
      float4 B4 = *(const float4*)(dr + 16 + q * 4);
      float Bj[4] = {B4.x, B4.y, B4.z, B4.w};
      #pragma unroll
      for (int j = 0; j < 4; j++) {
        int n = q * 4 + j;
        float a = __expf(dtv * A[n]);
        S[n] = a * S[n] + w * Bj[j];
      }
    }
  }
  float2* pp = ps + (size_t)c * 131072 + b * 8192 + d;
  #pragma unroll
  for (int n = 0; n < 16; n++)
    pp[(size_t)n * 512] = make_float2(__expf(A[n] * dtsum), S[n]);
}

__global__ __launch_bounds__(256) void scan_part2(
    const float2* __restrict__ ps, float* __restrict__ hs)
{
  int idx = blockIdx.x * 256 + threadIdx.x; // 131072 = (b,n,d)
  float h = 0.f;
  #pragma unroll
  for (int c = 0; c < 16; c++) {
    float2 v = ps[(size_t)c * 131072 + idx];
    hs[(size_t)c * 131072 + idx] = h;
    h = v.x * h + v.y;
  }
}

__global__ __launch_bounds__(256) void scan_part3(
    const u16* __restrict__ xch, const u16* __restrict__ xcl,
    const float* __restrict__ dbl,
    const float* __restrict__ xz,   // dt at cols [0,512), z at cols [512,1024)
    const float* __restrict__ Alog, const float* __restrict__ Dp,
    const float* __restrict__ hs,
    u16* __restrict__ yh, u16* __restrict__ yl)
{
  int bx = blockIdx.x;                 // 512 blocks
  int c = bx & 15, b = (bx >> 4) & 15, dg = bx >> 8;
  int d = dg * 256 + threadIdx.x;
  int t0 = c * 32;

  float A[16];
  #pragma unroll
  for (int q = 0; q < 4; q++) {
    float4 a4 = *(const float4*)(Alog + d * 16 + q * 4);
    A[q * 4 + 0] = -__expf(a4.x); A[q * 4 + 1] = -__expf(a4.y);
    A[q * 4 + 2] = -__expf(a4.z); A[q * 4 + 3] = -__expf(a4.w);
  }
  float Dv = Dp[d];
  float h[16];
  {
    const float* hp = hs + (size_t)c * 131072 + b * 8192 + d;
    #pragma unroll
    for (int n = 0; n < 16; n++) h[n] = hp[(size_t)n * 512];
  }

  const float* dblb = dbl + (size_t)(b * 512 + t0) * 48;  // wave-uniform
  const u16* uph = xch + (size_t)(b * 512 + t0) * 512 + d;
  const u16* upl = xcl + (size_t)(b * 512 + t0) * 512 + d;
  const float* dtp = xz + (size_t)(b * 512 + t0) * 1024 + d;
  const float* zp  = xz + (size_t)(b * 512 + t0) * 1024 + 512 + d;
  u16* yhp = yh + (size_t)(b * 512 + t0) * 512 + d;
  u16* ylp = yl + (size_t)(b * 512 + t0) * 512 + d;

  #pragma unroll 2
  for (int t = 0; t < 32; t++) {
    const float* dr = dblb + t * 48;
    float dtv = dtp[(size_t)t * 1024];
    float u = bf2f(uph[t * 512]) + bf2f(upl[t * 512]);
    float w = dtv * u;
    float y = 0.f;
    #pragma unroll
    for (int q = 0; q < 4; q++) {
      float4 B4 = *(const float4*)(dr + 16 + q * 4);
      float4 C4 = *(const float4*)(dr + 32 + q * 4);
      float Bj[4] = {B4.x, B4.y, B4.z, B4.w};
      float Cj[4] = {C4.x, C4.y, C4.z, C4.w};
      #pragma unroll
      for (int j = 0; j < 4; j++) {
        int n = q * 4 + j;
        float a = __expf(dtv * A[n]);
        h[n] = a * h[n] + w * Bj[j];
        y += h[n] * Cj[j];
      }
    }
    float zv = zp[(size_t)t * 1024];
    float v = (y + u * Dv) * silu_f(zv);
    u16 hb = f2bf(v);
    yhp[t * 512] = hb;
    ylp[t * 512] = f2bf(v - bf2f(hb));
  }
}

__global__ void pool_kernel(const float* __restrict__ h, float* __restrict__ pooled) {
  int b = blockIdx.x, d = threadIdx.x;
  float s = 0.f;
  for (int l = 0; l < 512; l++) s += h[((size_t)(b * 512 + l)) * 256 + d];
  pooled[b * 256 + d] = s * (1.f / 512.f);
}

__global__ void small_gemm_kernel(const float* __restrict__ A, const float* __restrict__ W,
                                  const float* __restrict__ bias, float* __restrict__ C,
                                  int Mb, int N, int K) {
  int idx = blockIdx.x * blockDim.x + threadIdx.x;
  if (idx >= Mb * N) return;
  int b = idx / N, n = idx - b * N;
  float acc = bias[n];
  for (int k = 0; k < K; k++) acc += A[b * K + k] * W[n * K + k];
  C[idx] = acc;
}

__global__ void bcast_kernel(const float* __restrict__ s, u16* __restrict__ hh, u16* __restrict__ hl) {
  int idx = blockIdx.x * 256 + threadIdx.x; // over 8192*256
  int d = idx & 255;
  int b = idx >> 17;
  float v = s[b * 256 + d];
  u16 hb = f2bf(v);
  hh[idx] = hb;
  hl[idx] = f2bf(v - bf2f(hb));
}

extern "C" void kernel_launch(void* const* d_in, const int* in_sizes, int n_in,
                              void* d_out, int out_size, void* d_ws, size_t ws_size,
                              hipStream_t stream) {
  const float* x     = (const float*)d_in[0];
  const float* emb_W = (const float*)d_in[1];
  const float* emb_b = (const float*)d_in[2];
  const float* lat_W = (const float*)d_in[3];
  const float* lat_b = (const float*)d_in[4];
  const float* l2s_W = (const float*)d_in[5];
  const float* l2s_b = (const float*)d_in[6];
  const float* out_W = (const float*)d_in[7];
  const float* out_b = (const float*)d_in[8];

  char* base = (char*)d_ws;
  float*  h      = (float*) (base + 0);          //  8,388,608 B
  float*  xz     = (float*) (base + 8388608);    // 33,554,432
  float*  dbl    = (float*) (base + 41943040);   //  1,572,864
  float2* ps     = (float2*)(base + 43515904);   // 16,777,216
  float*  hs     = (float*) (base + 60293120);   //  8,388,608
  u16*    h_hi   = (u16*)   (base + 68681728);   //  4,194,304
  u16*    h_lo   = (u16*)   (base + 72876032);   //  4,194,304
  u16*    xc_hi  = (u16*)   (base + 77070336);   //  8,388,608
  u16*    xc_lo  = (u16*)   (base + 85458944);   //  8,388,608
  u16*    x_hi   = (u16*)   (base + 93847552);   //  1,048,576
  u16*    x_lo   = (u16*)   (base + 94896128);   //  1,048,576
  u16*    w_hi   = (u16*)   (base + 95944704);   //  3,407,872
  u16*    w_lo   = (u16*)   (base + 99352576);   //  3,407,872
  float*  pooled = (float*) (base + 102760448);  //     16,384
  float*  s_sml  = (float*) (base + 102776832);  //     16,384
  // y split aliases ps (ps dead once scan_part2 consumed it; Wout runs before next part1)
  u16* y_hi = (u16*)ps;
  u16* y_lo = (u16*)((char*)ps + 8388608);

  float* recon  = (float*)d_out;      // 8192*64
  float* latent = recon + 524288;     // 16*128

  dim3 blk(256);

  // ---- split pre-pass: x + all GEMM weights ----
  SplitList sl;
  const float* srcs[9] = {x, emb_W, out_W,
                          (const float*)d_in[9],  (const float*)d_in[12], (const float*)d_in[17],
                          (const float*)d_in[18], (const float*)d_in[21], (const float*)d_in[26]};
  size_t offs[9] = {0, 0, 16384, 32768, 557056, 606208, 868352, 1392640, 1441792};
  int    n4s[9]  = {131072, 4096, 4096, 131072, 12288, 65536, 131072, 12288, 65536};
  for (int t = 0; t < 9; t++) {
    sl.src[t] = srcs[t];
    sl.hi[t] = (t == 0) ? x_hi : w_hi + offs[t];
    sl.lo[t] = (t == 0) ? x_lo : w_lo + offs[t];
    sl.n4[t] = n4s[t];
  }
  int total4 = 557056;
  hipLaunchKernelGGL(split_kernel, dim3(total4 / 256), blk, 0, stream, sl, total4);

  // h = x @ emb_W.T + emb_b  (split out only)
  hipLaunchKernelGGL((gemm_mfma<true, false, true>), dim3(4, 64), blk, 0, stream,
                     x_hi, x_lo, 64, w_hi + 0, w_lo + 0, emb_b,
                     nullptr, h_hi, h_lo, MROWS, 256, 64);

  auto run_layer = [&](int base_in, size_t wpre, int i, bool foutH) {
    const float* cw   = (const float*)d_in[base_in + 1] + (size_t)i * 512 * 4;
    const float* cb   = (const float*)d_in[base_in + 2] + (size_t)i * 512;
    const float* Wdt  = (const float*)d_in[base_in + 4] + (size_t)i * 512 * 16;
    const float* bdt  = (const float*)d_in[base_in + 5] + (size_t)i * 512;
    const float* Alog = (const float*)d_in[base_in + 6] + (size_t)i * 512 * 16;
    const float* Dpp  = (const float*)d_in[base_in + 7] + (size_t)i * 512;
    const u16* WinH  = w_hi + wpre + (size_t)i * 262144;
    const u16* WinL  = w_lo + wpre + (size_t)i * 262144;
    const u16* WxH   = w_hi + wpre + 524288 + (size_t)i * 24576;
    const u16* WxL   = w_lo + wpre + 524288 + (size_t)i * 24576;
    const u16* WoutH = w_hi + wpre + 573440 + (size_t)i * 131072;
    const u16* WoutL = w_lo + wpre + 573440 + (size_t)i * 131072;

    // xz = h @ Win.T
    hipLaunchKernelGGL((gemm_mfma<false, true, false>), dim3(16, 64), blk, 0, stream,
                       h_hi, h_lo, 256, WinH, WinL, nullptr, xz, nullptr, nullptr, MROWS, 1024, 256);
    // xc = silu(conv(xz[:, :512]) + cb) -> split
    hipLaunchKernelGGL(conv_silu_kernel, dim3(MROWS * 512 / 256), blk, 0, stream,
                       xz, cw, cb, xc_hi, xc_lo);
    // dbl = xc @ Wx.T (N=48)
    hipLaunchKernelGGL((gemm_mfma<false, true, false>), dim3(1, 64), blk, 0, stream,
                       xc_hi, xc_lo, 512, WxH, WxL, nullptr, dbl, nullptr, nullptr, MROWS, 48, 512);
    // chunked scan (dt fused once, register-state)
    hipLaunchKernelGGL(scan_part1, dim3(512), blk, 0, stream,
                       xc_hi, xc_lo, dbl, Wdt, bdt, Alog, ps, xz);
    hipLaunchKernelGGL(scan_part2, dim3(131072 / 256), blk, 0, stream,
                       (const float2*)ps, hs);
    hipLaunchKernelGGL(scan_part3, dim3(512), blk, 0, stream,
                       xc_hi, xc_lo, dbl, xz, Alog, Dpp, hs, y_hi, y_lo);
    // h = y @ Wout.T
    if (foutH)
      hipLaunchKernelGGL((gemm_mfma<false, true, true>), dim3(4, 64), blk, 0, stream,
                         y_hi, y_lo, 512, WoutH, WoutL, nullptr, h, h_hi, h_lo, MROWS, 256, 512);
    else
      hipLaunchKernelGGL((gemm_mfma<false, false, true>), dim3(4, 64), blk, 0, stream,
                         y_hi, y_lo, 512, WoutH, WoutL, nullptr, nullptr, h_hi, h_lo, MROWS, 256, 512);
  };

  run_layer(9, 32768, 0, false);
  run_layer(9, 32768, 1, true);   // pool needs f32 h

  hipLaunchKernelGGL(pool_kernel, dim3(16), blk, 0, stream, h, pooled);
  hipLaunchKernelGGL(small_gemm_kernel, dim3((16 * 128 + 255) / 256), blk, 0, stream,
                     pooled, lat_W, lat_b, latent, 16, 128, 256);
  hipLaunchKernelGGL(small_gemm_kernel, dim3((16 * 256 + 255) / 256), blk, 0, stream,
                     latent, l2s_W, l2s_b, s_sml, 16, 256, 128);
  hipLaunchKernelGGL(bcast_kernel, dim3(8192 * 256 / 256), blk, 0, stream, s_sml, h_hi, h_lo);

  run_layer(18, 868352, 0, false);
  run_layer(18, 868352, 1, false);

  // recon = h @ out_W.T + out_b
  hipLaunchKernelGGL((gemm_mfma<true, true, false>), dim3(1, 64), blk, 0, stream,
                     h_hi, h_lo, 256, w_hi + 16384, w_lo + 16384, out_b,
                     recon, nullptr, nullptr, MROWS, 64, 256);
}